// Round 1
// baseline (699.268 us; speedup 1.0000x reference)
//
#include <hip/hip_runtime.h>
#include <math.h>

typedef unsigned short u16;
typedef __bf16  bf16x8 __attribute__((ext_vector_type(8)));
typedef float   f32x4  __attribute__((ext_vector_type(4)));

__device__ __forceinline__ u16 f2bf(float f) {
  unsigned u = __float_as_uint(f);
  u += 0x7fffu + ((u >> 16) & 1u);
  return (u16)(u >> 16);
}
__device__ __forceinline__ __bf16 f2bfv(float f) {
  return __builtin_bit_cast(__bf16, f2bf(f));
}
__device__ __forceinline__ void gl_lds16(const void* g, void* l) {
  __builtin_amdgcn_global_load_lds((__attribute__((address_space(1))) void*)(void*)g,
                                   (__attribute__((address_space(3))) void*)l, 16u, 0, 0u);
}
__device__ __forceinline__ f32x4 mfma16(bf16x8 a, bf16x8 b, f32x4 c) {
  return __builtin_amdgcn_mfma_f32_16x16x32_bf16(a, b, c, 0, 0, 0);
}

// ---------------- LayerNorm: fp32 in -> bf16 out, one block per row of 1024 ----------------
__global__ __launch_bounds__(256) void ln_kernel(const float* __restrict__ x,
    const float* __restrict__ g, const float* __restrict__ b, u16* __restrict__ out) {
  const long row = blockIdx.x;
  const int t = threadIdx.x;
  const float4 v = ((const float4*)(x + row * 1024))[t];
  float s  = v.x + v.y + v.z + v.w;
  float sq = v.x*v.x + v.y*v.y + v.z*v.z + v.w*v.w;
#pragma unroll
  for (int m = 1; m < 64; m <<= 1) { s += __shfl_xor(s, m); sq += __shfl_xor(sq, m); }
  __shared__ float ss[4], ssq[4];
  const int wave = t >> 6;
  if ((t & 63) == 0) { ss[wave] = s; ssq[wave] = sq; }
  __syncthreads();
  s  = ss[0] + ss[1] + ss[2] + ss[3];
  sq = ssq[0] + ssq[1] + ssq[2] + ssq[3];
  const float mu = s * (1.0f / 1024.0f);
  const float rs = rsqrtf(sq * (1.0f / 1024.0f) - mu * mu + 1e-5f);
  const float4 gg = ((const float4*)g)[t];
  const float4 bb = ((const float4*)b)[t];
  ushort4 o;
  o.x = f2bf((v.x - mu) * rs * gg.x + bb.x);
  o.y = f2bf((v.y - mu) * rs * gg.y + bb.y);
  o.z = f2bf((v.z - mu) * rs * gg.z + bb.z);
  o.w = f2bf((v.w - mu) * rs * gg.w + bb.w);
  ((ushort4*)(out + row * 1024))[t] = o;
}

// ---------------- fp32 -> bf16 cast (4M elements) ----------------
__global__ __launch_bounds__(256) void cast_kernel(const float* __restrict__ in, u16* __restrict__ out) {
  const long i = ((long)blockIdx.x * 256 + threadIdx.x) * 4;
  const float4 v = *(const float4*)(in + i);
  ushort4 o;
  o.x = f2bf(v.x); o.y = f2bf(v.y); o.z = f2bf(v.z); o.w = f2bf(v.w);
  *(ushort4*)(out + i) = o;
}

// ---------------- transpose + cast: in fp32 [R][C] -> out bf16 [C][R] (out_ld = R) -------
// grid: (C/64, R/64, batch)
__global__ __launch_bounds__(256) void tp_kernel(const float* __restrict__ in,
    u16* __restrict__ out, int C, long in_bs, long out_bs, int out_ld) {
  __shared__ u16 tile[64][65];
  in  += (long)blockIdx.z * in_bs;
  out += (long)blockIdx.z * out_bs;
  const int r0 = blockIdx.y << 6, c0 = blockIdx.x << 6;
  const int t = threadIdx.x;
  const int lr = t >> 4, lc = (t & 15) << 2;
#pragma unroll
  for (int i = 0; i < 4; i++) {
    const int row = lr + i * 16;
    const float4 v = *(const float4*)(in + (long)(r0 + row) * C + c0 + lc);
    tile[row][lc + 0] = f2bf(v.x); tile[row][lc + 1] = f2bf(v.y);
    tile[row][lc + 2] = f2bf(v.z); tile[row][lc + 3] = f2bf(v.w);
  }
  __syncthreads();
#pragma unroll
  for (int i = 0; i < 4; i++) {
    const int cc = lr + i * 16;
    ushort4 o;
    o.x = tile[lc + 0][cc]; o.y = tile[lc + 1][cc];
    o.z = tile[lc + 2][cc]; o.w = tile[lc + 3][cc];
    *(ushort4*)(out + (long)(c0 + cc) * out_ld + r0 + lc) = o;
  }
}

// ---------------- GEMM: C = A[M,K](bf16) @ BT[N,K]^T(bf16) + bias, fused epilogues -------
// MODE 0: N=3072 fused QKV -> o0 Q[B,H,S,D], o1 K[B,H,S,D], o2 VT[B,H,D,S]
// MODE 1: N=2048 fused KV  -> o0 K[B,H,S,D], o1 VT[B,H,D,S]
// MODE 2: Q only           -> o0 Q[B,H,S,D]
// MODE 3: fp32 residual    -> of[row*N+col] = acc + b0[col] + res[row*N+col]
// MODE 4: GELU bf16        -> o0[row*N+col] = gelu(acc + b0[col])
template<int MFRAG, int MODE>
__global__ __launch_bounds__(256, 2) void gemm_kernel(
    const u16* __restrict__ A, const u16* __restrict__ BT,
    const float* __restrict__ b0, const float* __restrict__ b1, const float* __restrict__ b2,
    const float* __restrict__ res,
    u16* __restrict__ o0, u16* __restrict__ o1, u16* __restrict__ o2,
    float* __restrict__ of, int M, int N, int K)
{
  constexpr int BM = MFRAG * 32;
  __shared__ __bf16 As[BM * 64];
  __shared__ __bf16 Bs[128 * 64];
  const int tid = threadIdx.x;
  const int wave = tid >> 6, lane = tid & 63;
  const int g = lane >> 4, li = lane & 15;
  const long m0 = (long)blockIdx.y * BM;
  const int  n0 = blockIdx.x << 7;
  const int  wr = wave >> 1, wc = wave & 1;

  f32x4 acc[MFRAG][4] = {};

  const u16* Ag = A + (m0 + wave * (MFRAG * 8) + (lane >> 3)) * K + ((lane & 7) << 3);
  const u16* Bg = BT + ((long)(n0 + wave * 32 + (lane >> 3))) * K + ((lane & 7) << 3);
  __bf16* AsW = As + wave * (MFRAG * 512);
  __bf16* BsW = Bs + wave * 2048;

  for (int k0 = 0; k0 < K; k0 += 64) {
#pragma unroll
    for (int i = 0; i < MFRAG; i++)
      gl_lds16(Ag + (long)i * 8 * K + k0, AsW + i * 512);
#pragma unroll
    for (int i = 0; i < 4; i++)
      gl_lds16(Bg + (long)i * 8 * K + k0, BsW + i * 512);
    __syncthreads();
#pragma unroll
    for (int kk = 0; kk < 2; kk++) {
      bf16x8 af[MFRAG], bv[4];
#pragma unroll
      for (int m = 0; m < MFRAG; m++)
        af[m] = *(const bf16x8*)&As[(wr * (MFRAG * 16) + m * 16 + li) * 64 + kk * 32 + g * 8];
#pragma unroll
      for (int n = 0; n < 4; n++)
        bv[n] = *(const bf16x8*)&Bs[(wc * 64 + n * 16 + li) * 64 + kk * 32 + g * 8];
#pragma unroll
      for (int m = 0; m < MFRAG; m++)
#pragma unroll
        for (int n = 0; n < 4; n++)
          acc[m][n] = mfma16(af[m], bv[n], acc[m][n]);
    }
    __syncthreads();
  }

#pragma unroll
  for (int m = 0; m < MFRAG; m++) {
#pragma unroll
    for (int n = 0; n < 4; n++) {
      const int col = n0 + wc * 64 + n * 16 + li;
#pragma unroll
      for (int r = 0; r < 4; r++) {
        const int row = (int)m0 + wr * (MFRAG * 16) + m * 16 + g * 4 + r;
        float v = acc[m][n][r];
        if constexpr (MODE == 0) {
          const int sel = col >> 10, cl = col & 1023;
          v += (sel == 0 ? b0 : sel == 1 ? b1 : b2)[cl];
          const int bI = row >> 10, sI = row & 1023, hI = cl >> 6, dI = cl & 63;
          if (sel < 2) (sel == 0 ? o0 : o1)[((long)(bI * 16 + hI) * 1024 + sI) * 64 + dI] = f2bf(v);
          else         o2[((long)(bI * 16 + hI) * 64 + dI) * 1024 + sI] = f2bf(v);
        } else if constexpr (MODE == 1) {
          const int sel = col >> 10, cl = col & 1023;
          v += (sel == 0 ? b0 : b1)[cl];
          const int bI = row >> 10, sI = row & 1023, hI = cl >> 6, dI = cl & 63;
          if (sel == 0) o0[((long)(bI * 16 + hI) * 1024 + sI) * 64 + dI] = f2bf(v);
          else          o1[((long)(bI * 16 + hI) * 64 + dI) * 1024 + sI] = f2bf(v);
        } else if constexpr (MODE == 2) {
          v += b0[col];
          const int bI = row >> 10, sI = row & 1023, hI = col >> 6, dI = col & 63;
          o0[((long)(bI * 16 + hI) * 1024 + sI) * 64 + dI] = f2bf(v);
        } else if constexpr (MODE == 3) {
          v += b0[col];
          const long idx = (long)row * N + col;
          of[idx] = v + res[idx];
        } else {
          v += b0[col];
          const float gl = 0.5f * v * (1.0f + erff(v * 0.70710678118654752f));
          o0[(long)row * N + col] = f2bf(gl);
        }
      }
    }
  }
}

// ---------------- flash attention: Q[BH,S,64], K[BH,S,64], VT[BH,64,S] -> O[B,S,1024] ----
// grid (S/64, B*H), 256 threads; wave w owns 16 q-rows. No 1/sqrt(d) scale (faithful).
__global__ __launch_bounds__(256, 2) void attn_kernel(
    const u16* __restrict__ Q, const u16* __restrict__ Kb,
    const u16* __restrict__ VT, u16* __restrict__ O, const int causal)
{
  __shared__ __bf16 Ks[32 * 64];
  __shared__ __bf16 Vs[64 * 32];
  __shared__ __bf16 Ps[4][512];
  const int tid = threadIdx.x;
  const int wave = tid >> 6, lane = tid & 63;
  const int g = lane >> 4, li = lane & 15;
  const int qt = blockIdx.x, bh = blockIdx.y;
  const int b_ = bh >> 4, h_ = bh & 15;
  const int q_lo = qt * 64 + wave * 16;

  const u16* Qp = Q + ((long)bh * 1024 + q_lo + li) * 64 + g * 8;
  const bf16x8 aq0 = *(const bf16x8*)Qp;
  const bf16x8 aq1 = *(const bf16x8*)(Qp + 32);

  f32x4 acc[4] = {};
  float mrun[4] = {-1e30f, -1e30f, -1e30f, -1e30f};
  float lrun[4] = {0.f, 0.f, 0.f, 0.f};

  const u16* Kg = Kb + ((long)bh * 1024 + wave * 8 + (lane >> 3)) * 64 + ((lane & 7) << 3);
  const u16* Vg = VT + ((long)bh * 64 + wave * 16 + (lane >> 2)) * 1024 + ((lane & 3) << 3);
  __bf16* KsW = Ks + wave * 512;
  __bf16* VsW = Vs + wave * 512;

  const int nk = causal ? (qt + 1) * 2 : 32;
  for (int kt = 0; kt < nk; kt++) {
    const int k0 = kt * 32;
    gl_lds16(Kg + (long)k0 * 64, KsW);
    gl_lds16(Vg + k0, VsW);
    __syncthreads();

    f32x4 s0 = {}, s1 = {};
    {
      const bf16x8 b00 = *(const bf16x8*)&Ks[(li) * 64 + g * 8];
      const bf16x8 b01 = *(const bf16x8*)&Ks[(li) * 64 + 32 + g * 8];
      const bf16x8 b10 = *(const bf16x8*)&Ks[(16 + li) * 64 + g * 8];
      const bf16x8 b11 = *(const bf16x8*)&Ks[(16 + li) * 64 + 32 + g * 8];
      s0 = mfma16(aq0, b00, s0); s0 = mfma16(aq1, b01, s0);
      s1 = mfma16(aq0, b10, s1); s1 = mfma16(aq1, b11, s1);
    }
    if (causal && (k0 + 31 > q_lo)) {
#pragma unroll
      for (int r = 0; r < 4; r++) {
        const int q = q_lo + g * 4 + r;
        if (k0 + li > q)      s0[r] = -1e30f;
        if (k0 + 16 + li > q) s1[r] = -1e30f;
      }
    }
#pragma unroll
    for (int r = 0; r < 4; r++) {
      float pm = fmaxf(s0[r], s1[r]);
      pm = fmaxf(pm, __shfl_xor(pm, 1));
      pm = fmaxf(pm, __shfl_xor(pm, 2));
      pm = fmaxf(pm, __shfl_xor(pm, 4));
      pm = fmaxf(pm, __shfl_xor(pm, 8));
      const float mnew = fmaxf(mrun[r], pm);
      const float p0 = expf(s0[r] - mnew);
      const float p1 = expf(s1[r] - mnew);
      Ps[wave][(g * 4 + r) * 32 + li]      = f2bfv(p0);
      Ps[wave][(g * 4 + r) * 32 + 16 + li] = f2bfv(p1);
      float rsum = p0 + p1;
      rsum += __shfl_xor(rsum, 1);
      rsum += __shfl_xor(rsum, 2);
      rsum += __shfl_xor(rsum, 4);
      rsum += __shfl_xor(rsum, 8);
      const float sc = expf(mrun[r] - mnew);
      mrun[r] = mnew;
      lrun[r] = lrun[r] * sc + rsum;
      acc[0][r] *= sc; acc[1][r] *= sc; acc[2][r] *= sc; acc[3][r] *= sc;
    }
    const bf16x8 pa = *(const bf16x8*)&Ps[wave][li * 32 + g * 8];
#pragma unroll
    for (int n = 0; n < 4; n++) {
      const bf16x8 bv = *(const bf16x8*)&Vs[(n * 16 + li) * 32 + g * 8];
      acc[n] = mfma16(pa, bv, acc[n]);
    }
    __syncthreads();
  }

#pragma unroll
  for (int r = 0; r < 4; r++) {
    const int q = q_lo + g * 4 + r;
    const float inv = 1.0f / lrun[r];
#pragma unroll
    for (int n = 0; n < 4; n++)
      O[((long)b_ * 1024 + q) * 1024 + h_ * 64 + n * 16 + li] = f2bf(acc[n][r] * inv);
  }
}

// ---------------------------------------------------------------------------------------
extern "C" void kernel_launch(void* const* d_in, const int* in_sizes, int n_in,
                              void* d_out, int out_size, void* d_ws, size_t ws_size,
                              hipStream_t stream) {
  const float* x     = (const float*)d_in[0];
  const float* enc   = (const float*)d_in[1];
  const float* ln1_g = (const float*)d_in[2];
  const float* ln1_b = (const float*)d_in[3];
  const float* ln2_g = (const float*)d_in[4];
  const float* ln2_b = (const float*)d_in[5];
  const float* ln3_g = (const float*)d_in[6];
  const float* ln3_b = (const float*)d_in[7];
  const float* Wq1 = (const float*)d_in[8];  const float* bq1 = (const float*)d_in[9];
  const float* Wk1 = (const float*)d_in[10]; const float* bk1 = (const float*)d_in[11];
  const float* Wv1 = (const float*)d_in[12]; const float* bv1 = (const float*)d_in[13];
  const float* Wo1 = (const float*)d_in[14]; const float* bo1 = (const float*)d_in[15];
  const float* Wq2 = (const float*)d_in[16]; const float* bq2 = (const float*)d_in[17];
  const float* Wk2 = (const float*)d_in[18]; const float* bk2 = (const float*)d_in[19];
  const float* Wv2 = (const float*)d_in[20]; const float* bv2 = (const float*)d_in[21];
  const float* Wo2 = (const float*)d_in[22]; const float* bo2 = (const float*)d_in[23];
  const float* Wup = (const float*)d_in[24]; const float* bup = (const float*)d_in[25];
  const float* Wdn = (const float*)d_in[26]; const float* bdn = (const float*)d_in[27];

  char* ws = (char*)d_ws;
  const size_t MB = 1ull << 20;
  u16*   wpack  = (u16*)(ws);             // <= 8MB packed bf16 B^T weights (reused)
  u16*   enc_bf = (u16*)(ws + 8 * MB);
  u16*   h_bf   = (u16*)(ws + 16 * MB);
  u16*   Qb     = (u16*)(ws + 24 * MB);
  u16*   Kbf    = (u16*)(ws + 32 * MB);
  u16*   VTb    = (u16*)(ws + 40 * MB);
  u16*   att_o  = (u16*)(ws + 48 * MB);
  float* x2     = (float*)(ws + 56 * MB);
  float* x3     = (float*)(ws + 72 * MB);
  u16*   ffmid  = (u16*)(ws + 24 * MB);   // overlaps Q/K/VT/att_o (dead by FFN)

  const dim3 T(256);

  // ---- block 1: self attention ----
  ln_kernel<<<4096, T, 0, stream>>>(x, ln1_g, ln1_b, h_bf);
  cast_kernel<<<4096, T, 0, stream>>>(enc, enc_bf);
  tp_kernel<<<dim3(1, 16, 16), T, 0, stream>>>(Wq1, wpack,              64, 65536L, 65536L, 1024);
  tp_kernel<<<dim3(1, 16, 16), T, 0, stream>>>(Wk1, wpack + 1024 * 1024, 64, 65536L, 65536L, 1024);
  tp_kernel<<<dim3(1, 16, 16), T, 0, stream>>>(Wv1, wpack + 2048 * 1024, 64, 65536L, 65536L, 1024);
  gemm_kernel<4, 0><<<dim3(24, 32), T, 0, stream>>>(h_bf, wpack, bq1, bk1, bv1, nullptr,
      Qb, Kbf, VTb, nullptr, 4096, 3072, 1024);
  attn_kernel<<<dim3(16, 64), T, 0, stream>>>(Qb, Kbf, VTb, att_o, 1);
  tp_kernel<<<dim3(16, 16, 1), T, 0, stream>>>(Wo1, wpack, 1024, 0L, 0L, 1024);
  gemm_kernel<2, 3><<<dim3(8, 64), T, 0, stream>>>(att_o, wpack, bo1, nullptr, nullptr, x,
      nullptr, nullptr, nullptr, x2, 4096, 1024, 1024);

  // ---- block 2: cross attention (K/V from raw enc) ----
  ln_kernel<<<4096, T, 0, stream>>>(x2, ln2_g, ln2_b, h_bf);
  tp_kernel<<<dim3(1, 16, 16), T, 0, stream>>>(Wq2, wpack, 64, 65536L, 65536L, 1024);
  gemm_kernel<2, 2><<<dim3(8, 64), T, 0, stream>>>(h_bf, wpack, bq2, nullptr, nullptr, nullptr,
      Qb, nullptr, nullptr, nullptr, 4096, 1024, 1024);
  tp_kernel<<<dim3(1, 16, 16), T, 0, stream>>>(Wk2, wpack,              64, 65536L, 65536L, 1024);
  tp_kernel<<<dim3(1, 16, 16), T, 0, stream>>>(Wv2, wpack + 1024 * 1024, 64, 65536L, 65536L, 1024);
  gemm_kernel<4, 1><<<dim3(16, 32), T, 0, stream>>>(enc_bf, wpack, bk2, bv2, nullptr, nullptr,
      Kbf, VTb, nullptr, nullptr, 4096, 2048, 1024);
  attn_kernel<<<dim3(16, 64), T, 0, stream>>>(Qb, Kbf, VTb, att_o, 0);
  tp_kernel<<<dim3(16, 16, 1), T, 0, stream>>>(Wo2, wpack, 1024, 0L, 0L, 1024);
  gemm_kernel<2, 3><<<dim3(8, 64), T, 0, stream>>>(att_o, wpack, bo2, nullptr, nullptr, x2,
      nullptr, nullptr, nullptr, x3, 4096, 1024, 1024);

  // ---- block 3: FFN ----
  ln_kernel<<<4096, T, 0, stream>>>(x3, ln3_g, ln3_b, h_bf);
  tp_kernel<<<dim3(64, 16, 1), T, 0, stream>>>(Wup, wpack, 4096, 0L, 0L, 1024);
  gemm_kernel<4, 4><<<dim3(32, 32), T, 0, stream>>>(h_bf, wpack, bup, nullptr, nullptr, nullptr,
      ffmid, nullptr, nullptr, nullptr, 4096, 4096, 1024);
  tp_kernel<<<dim3(16, 64, 1), T, 0, stream>>>(Wdn, wpack, 1024, 0L, 0L, 4096);
  gemm_kernel<2, 3><<<dim3(8, 64), T, 0, stream>>>(ffmid, wpack, bdn, nullptr, nullptr, x3,
      nullptr, nullptr, nullptr, (float*)d_out, 4096, 1024, 4096);
}

// Round 2
// 604.100 us; speedup vs baseline: 1.1575x; 1.1575x over previous
//
#include <hip/hip_runtime.h>
#include <math.h>

typedef unsigned short u16;
typedef __bf16  bf16x8 __attribute__((ext_vector_type(8)));
typedef float   f32x4  __attribute__((ext_vector_type(4)));

__device__ __forceinline__ u16 f2bf(float f) {
  unsigned u = __float_as_uint(f);
  u += 0x7fffu + ((u >> 16) & 1u);
  return (u16)(u >> 16);
}
__device__ __forceinline__ void gl_lds16(const void* g, void* l) {
  __builtin_amdgcn_global_load_lds((__attribute__((address_space(1))) void*)(void*)g,
                                   (__attribute__((address_space(3))) void*)l, 16u, 0, 0u);
}
__device__ __forceinline__ f32x4 mfma16(bf16x8 a, bf16x8 b, f32x4 c) {
  return __builtin_amdgcn_mfma_f32_16x16x32_bf16(a, b, c, 0, 0, 0);
}

// ---------------- LayerNorm: fp32 in -> bf16 out, one block per row of 1024 ----------------
__global__ __launch_bounds__(256) void ln_kernel(const float* __restrict__ x,
    const float* __restrict__ g, const float* __restrict__ b, u16* __restrict__ out) {
  const long row = blockIdx.x;
  const int t = threadIdx.x;
  const float4 v = ((const float4*)(x + row * 1024))[t];
  float s  = v.x + v.y + v.z + v.w;
  float sq = v.x*v.x + v.y*v.y + v.z*v.z + v.w*v.w;
#pragma unroll
  for (int m = 1; m < 64; m <<= 1) { s += __shfl_xor(s, m); sq += __shfl_xor(sq, m); }
  __shared__ float ss[4], ssq[4];
  const int wave = t >> 6;
  if ((t & 63) == 0) { ss[wave] = s; ssq[wave] = sq; }
  __syncthreads();
  s  = ss[0] + ss[1] + ss[2] + ss[3];
  sq = ssq[0] + ssq[1] + ssq[2] + ssq[3];
  const float mu = s * (1.0f / 1024.0f);
  const float rs = rsqrtf(sq * (1.0f / 1024.0f) - mu * mu + 1e-5f);
  const float4 gg = ((const float4*)g)[t];
  const float4 bb = ((const float4*)b)[t];
  ushort4 o;
  o.x = f2bf((v.x - mu) * rs * gg.x + bb.x);
  o.y = f2bf((v.y - mu) * rs * gg.y + bb.y);
  o.z = f2bf((v.z - mu) * rs * gg.z + bb.z);
  o.w = f2bf((v.w - mu) * rs * gg.w + bb.w);
  ((ushort4*)(out + row * 1024))[t] = o;
}

// ---------------- fp32 -> bf16 cast (4M elements) ----------------
__global__ __launch_bounds__(256) void cast_kernel(const float* __restrict__ in, u16* __restrict__ out) {
  const long i = ((long)blockIdx.x * 256 + threadIdx.x) * 4;
  const float4 v = *(const float4*)(in + i);
  ushort4 o;
  o.x = f2bf(v.x); o.y = f2bf(v.y); o.z = f2bf(v.z); o.w = f2bf(v.w);
  *(ushort4*)(out + i) = o;
}

// ---------------- transpose + cast: in fp32 [R][C] -> out bf16 [C][R] (out_ld = R) -------
__global__ __launch_bounds__(256) void tp_kernel(const float* __restrict__ in,
    u16* __restrict__ out, int C, long in_bs, long out_bs, int out_ld) {
  __shared__ u16 tile[64][65];
  in  += (long)blockIdx.z * in_bs;
  out += (long)blockIdx.z * out_bs;
  const int r0 = blockIdx.y << 6, c0 = blockIdx.x << 6;
  const int t = threadIdx.x;
  const int lr = t >> 4, lc = (t & 15) << 2;
#pragma unroll
  for (int i = 0; i < 4; i++) {
    const int row = lr + i * 16;
    const float4 v = *(const float4*)(in + (long)(r0 + row) * C + c0 + lc);
    tile[row][lc + 0] = f2bf(v.x); tile[row][lc + 1] = f2bf(v.y);
    tile[row][lc + 2] = f2bf(v.z); tile[row][lc + 3] = f2bf(v.w);
  }
  __syncthreads();
#pragma unroll
  for (int i = 0; i < 4; i++) {
    const int cc = lr + i * 16;
    ushort4 o;
    o.x = tile[lc + 0][cc]; o.y = tile[lc + 1][cc];
    o.z = tile[lc + 2][cc]; o.w = tile[lc + 3][cc];
    *(ushort4*)(out + (long)(c0 + cc) * out_ld + r0 + lc) = o;
  }
}

// ---------------- GEMM: C = A[M,K](bf16) @ BT[N,K]^T(bf16) + bias, fused epilogues -------
// K is written SWIZZLED:  K[bh][s][d ^ ((s&7)<<3)]
// VT is written SWIZZLED: VT[bh][d][(s&~63) + ((s&63) ^ ((d&7)<<3))]
// MODE 0: N=3072 fused QKV -> o0 Q, o1 K(swz), o2 VT(swz)
// MODE 1: N=2048 fused KV  -> o0 K(swz), o1 VT(swz)
// MODE 2: Q only           -> o0 Q
// MODE 3: fp32 residual    -> of = acc + b0 + res
// MODE 4: GELU bf16        -> o0 = gelu(acc + b0)
template<int MFRAG, int MODE>
__global__ __launch_bounds__(256, 2) void gemm_kernel(
    const u16* __restrict__ A, const u16* __restrict__ BT,
    const float* __restrict__ b0, const float* __restrict__ b1, const float* __restrict__ b2,
    const float* __restrict__ res,
    u16* __restrict__ o0, u16* __restrict__ o1, u16* __restrict__ o2,
    float* __restrict__ of, int M, int N, int K)
{
  constexpr int BM = MFRAG * 32;
  __shared__ __bf16 As[BM * 64];
  __shared__ __bf16 Bs[128 * 64];
  const int tid = threadIdx.x;
  const int wave = tid >> 6, lane = tid & 63;
  const int g = lane >> 4, li = lane & 15;
  const long m0 = (long)blockIdx.y * BM;
  const int  n0 = blockIdx.x << 7;
  const int  wr = wave >> 1, wc = wave & 1;

  f32x4 acc[MFRAG][4] = {};

  const u16* Ag = A + (m0 + wave * (MFRAG * 8) + (lane >> 3)) * K + ((lane & 7) << 3);
  const u16* Bg = BT + ((long)(n0 + wave * 32 + (lane >> 3))) * K + ((lane & 7) << 3);
  __bf16* AsW = As + wave * (MFRAG * 512);
  __bf16* BsW = Bs + wave * 2048;

  for (int k0 = 0; k0 < K; k0 += 64) {
#pragma unroll
    for (int i = 0; i < MFRAG; i++)
      gl_lds16(Ag + (long)i * 8 * K + k0, AsW + i * 512);
#pragma unroll
    for (int i = 0; i < 4; i++)
      gl_lds16(Bg + (long)i * 8 * K + k0, BsW + i * 512);
    __syncthreads();
#pragma unroll
    for (int kk = 0; kk < 2; kk++) {
      bf16x8 af[MFRAG], bv[4];
#pragma unroll
      for (int m = 0; m < MFRAG; m++)
        af[m] = *(const bf16x8*)&As[(wr * (MFRAG * 16) + m * 16 + li) * 64 + kk * 32 + g * 8];
#pragma unroll
      for (int n = 0; n < 4; n++)
        bv[n] = *(const bf16x8*)&Bs[(wc * 64 + n * 16 + li) * 64 + kk * 32 + g * 8];
#pragma unroll
      for (int m = 0; m < MFRAG; m++)
#pragma unroll
        for (int n = 0; n < 4; n++)
          acc[m][n] = mfma16(af[m], bv[n], acc[m][n]);
    }
    __syncthreads();
  }

#pragma unroll
  for (int m = 0; m < MFRAG; m++) {
#pragma unroll
    for (int n = 0; n < 4; n++) {
      const int col = n0 + wc * 64 + n * 16 + li;
#pragma unroll
      for (int r = 0; r < 4; r++) {
        const int row = (int)m0 + wr * (MFRAG * 16) + m * 16 + g * 4 + r;
        float v = acc[m][n][r];
        if constexpr (MODE == 0 || MODE == 1) {
          const int sel = col >> 10, cl = col & 1023;
          v += (MODE == 0 ? (sel == 0 ? b0 : sel == 1 ? b1 : b2)
                          : (sel == 0 ? b0 : b1))[cl];
          const int bI = row >> 10, sI = row & 1023, hI = cl >> 6, dI = cl & 63;
          const long bhI = (long)(bI * 16 + hI);
          const int qsel = (MODE == 0) ? 0 : -1;      // MODE0: sel0=Q; MODE1: sel0=K
          if (sel == qsel) {
            o0[(bhI * 1024 + sI) * 64 + dI] = f2bf(v);           // Q linear
          } else if (sel == qsel + 1) {
            u16* Kp = (MODE == 0) ? o1 : o0;
            Kp[(bhI * 1024 + sI) * 64 + (dI ^ ((sI & 7) << 3))] = f2bf(v);  // K swizzled
          } else {
            u16* Vp = (MODE == 0) ? o2 : o1;
            Vp[(bhI * 64 + dI) * 1024 + (sI & ~63) + ((sI & 63) ^ ((dI & 7) << 3))] = f2bf(v); // VT swizzled
          }
        } else if constexpr (MODE == 2) {
          v += b0[col];
          const int bI = row >> 10, sI = row & 1023, hI = col >> 6, dI = col & 63;
          o0[((long)(bI * 16 + hI) * 1024 + sI) * 64 + dI] = f2bf(v);
        } else if constexpr (MODE == 3) {
          v += b0[col];
          const long idx = (long)row * N + col;
          of[idx] = v + res[idx];
        } else {
          v += b0[col];
          const float gl = 0.5f * v * (1.0f + erff(v * 0.70710678118654752f));
          o0[(long)row * N + col] = f2bf(gl);
        }
      }
    }
  }
}

// ---------------- flash attention: Q[BH,S,64], K(swz)[BH,S,64], VT(swz)[BH,64,S] ----------
// grid (S/64, B*H), 256 threads; wave w owns 16 q-rows; KV tile = 64, double-buffered.
__global__ __launch_bounds__(256, 2) void attn_kernel(
    const u16* __restrict__ Q, const u16* __restrict__ Kb,
    const u16* __restrict__ VT, u16* __restrict__ O, const int causal)
{
  __shared__ u16 Ks[2][4096];   // [64 keys][64 dims], dim ^ ((key&7)<<3)
  __shared__ u16 Vs[2][4096];   // [64 dims][64 keys], key ^ ((dim&7)<<3)
  __shared__ u16 Ps[4][1024];   // per-wave [16 q][64 k], k ^ ((q&7)<<3)
  const int tid = threadIdx.x;
  const int wave = tid >> 6, lane = tid & 63;
  const int g = lane >> 4, li = lane & 15;
  const int qt = blockIdx.x, bh = blockIdx.y;
  const int b_ = bh >> 4, h_ = bh & 15;
  const int q_lo = qt * 64 + wave * 16;

  const u16* Qp = Q + ((long)bh * 1024 + q_lo + li) * 64 + g * 8;
  const bf16x8 aq0 = *(const bf16x8*)Qp;
  const bf16x8 aq1 = *(const bf16x8*)(Qp + 32);

  f32x4 acc[4] = {};
  float mrun[4] = {-1e30f, -1e30f, -1e30f, -1e30f};
  float lrun[4] = {0.f, 0.f, 0.f, 0.f};

  const u16* Kbh = Kb + (long)bh * 65536;
  const u16* Vbh = VT + (long)bh * 65536;
  const int swl = (li & 7) << 3;

  const int nk = causal ? (qt + 1) : 16;

  // prologue: stage tile 0 into buf 0 (K tile is 8KB contiguous; V tile strided by d-row)
#pragma unroll
  for (int i = 0; i < 2; i++) {
    const int bc = i * 256 + wave * 64;
    gl_lds16(Kbh + (long)(bc + lane) * 8, &Ks[0][bc * 8]);
    const int ci = bc + lane, d = ci >> 3, c = ci & 7;
    gl_lds16(Vbh + (long)d * 1024 + c * 8, &Vs[0][bc * 8]);
  }
  __syncthreads();

  for (int kt = 0; kt < nk; kt++) {
    const int buf = kt & 1;
    const int k0 = kt * 64;
    if (kt + 1 < nk) {
      const int nb = buf ^ 1;
#pragma unroll
      for (int i = 0; i < 2; i++) {
        const int bc = i * 256 + wave * 64;
        gl_lds16(Kbh + (long)(kt + 1) * 4096 + (long)(bc + lane) * 8, &Ks[nb][bc * 8]);
        const int ci = bc + lane, d = ci >> 3, c = ci & 7;
        gl_lds16(Vbh + (long)d * 1024 + (kt + 1) * 64 + c * 8, &Vs[nb][bc * 8]);
      }
    }

    // ---- QK^T: S[q][k], 8 MFMA ----
    f32x4 s[4] = {};
#pragma unroll
    for (int n = 0; n < 4; n++) {
      const u16* kp = &Ks[buf][(n * 16 + li) * 64];
      const bf16x8 bk0 = *(const bf16x8*)(kp + ((g * 8) ^ swl));
      const bf16x8 bk1 = *(const bf16x8*)(kp + ((32 + g * 8) ^ swl));
      s[n] = mfma16(aq0, bk0, s[n]);
      s[n] = mfma16(aq1, bk1, s[n]);
    }

    if (causal && k0 + 63 > q_lo) {
#pragma unroll
      for (int n = 0; n < 4; n++) {
        const int key = k0 + n * 16 + li;
#pragma unroll
        for (int r = 0; r < 4; r++)
          if (key > q_lo + g * 4 + r) s[n][r] = -1e30f;
      }
    }

    // ---- online softmax (row = q_lo + g*4 + r, cols spread over li) ----
    float pmax[4];
#pragma unroll
    for (int r = 0; r < 4; r++) {
      float pm = fmaxf(fmaxf(s[0][r], s[1][r]), fmaxf(s[2][r], s[3][r]));
      pm = fmaxf(pm, __shfl_xor(pm, 1));
      pm = fmaxf(pm, __shfl_xor(pm, 2));
      pm = fmaxf(pm, __shfl_xor(pm, 4));
      pm = fmaxf(pm, __shfl_xor(pm, 8));
      pmax[r] = pm;
    }
    const bool need = (pmax[0] > mrun[0] + 8.f) || (pmax[1] > mrun[1] + 8.f) ||
                      (pmax[2] > mrun[2] + 8.f) || (pmax[3] > mrun[3] + 8.f);
    if (__any(need)) {
#pragma unroll
      for (int r = 0; r < 4; r++) {
        const float mnew = fmaxf(mrun[r], pmax[r]);
        const float sc = __expf(mrun[r] - mnew);
        mrun[r] = mnew;
        lrun[r] *= sc;
        acc[0][r] *= sc; acc[1][r] *= sc; acc[2][r] *= sc; acc[3][r] *= sc;
      }
    }
#pragma unroll
    for (int r = 0; r < 4; r++) {
      const int q = g * 4 + r;
      const int swq = (q & 7) << 3;
      const float p0 = __expf(s[0][r] - mrun[r]);
      const float p1 = __expf(s[1][r] - mrun[r]);
      const float p2 = __expf(s[2][r] - mrun[r]);
      const float p3 = __expf(s[3][r] - mrun[r]);
      u16* pw = &Ps[wave][q * 64];
      pw[(li)      ^ swq] = f2bf(p0);
      pw[(16 + li) ^ swq] = f2bf(p1);
      pw[(32 + li) ^ swq] = f2bf(p2);
      pw[(48 + li) ^ swq] = f2bf(p3);
      float rs_ = (p0 + p1) + (p2 + p3);
      rs_ += __shfl_xor(rs_, 1);
      rs_ += __shfl_xor(rs_, 2);
      rs_ += __shfl_xor(rs_, 4);
      rs_ += __shfl_xor(rs_, 8);
      lrun[r] += rs_;
    }

    // ---- PV: acc[d-group], 8 MFMA ----
    const bf16x8 pa0 = *(const bf16x8*)&Ps[wave][li * 64 + ((g * 8) ^ swl)];
    const bf16x8 pa1 = *(const bf16x8*)&Ps[wave][li * 64 + ((32 + g * 8) ^ swl)];
#pragma unroll
    for (int n = 0; n < 4; n++) {
      const u16* vp = &Vs[buf][(n * 16 + li) * 64];
      const bf16x8 v0 = *(const bf16x8*)(vp + ((g * 8) ^ swl));
      const bf16x8 v1 = *(const bf16x8*)(vp + ((32 + g * 8) ^ swl));
      acc[n] = mfma16(pa0, v0, acc[n]);
      acc[n] = mfma16(pa1, v1, acc[n]);
    }
    __syncthreads();
  }

#pragma unroll
  for (int r = 0; r < 4; r++) {
    const int q = q_lo + g * 4 + r;
    const float inv = 1.0f / lrun[r];
#pragma unroll
    for (int n = 0; n < 4; n++)
      O[((long)b_ * 1024 + q) * 1024 + h_ * 64 + n * 16 + li] = f2bf(acc[n][r] * inv);
  }
}

// ---------------------------------------------------------------------------------------
extern "C" void kernel_launch(void* const* d_in, const int* in_sizes, int n_in,
                              void* d_out, int out_size, void* d_ws, size_t ws_size,
                              hipStream_t stream) {
  const float* x     = (const float*)d_in[0];
  const float* enc   = (const float*)d_in[1];
  const float* ln1_g = (const float*)d_in[2];
  const float* ln1_b = (const float*)d_in[3];
  const float* ln2_g = (const float*)d_in[4];
  const float* ln2_b = (const float*)d_in[5];
  const float* ln3_g = (const float*)d_in[6];
  const float* ln3_b = (const float*)d_in[7];
  const float* Wq1 = (const float*)d_in[8];  const float* bq1 = (const float*)d_in[9];
  const float* Wk1 = (const float*)d_in[10]; const float* bk1 = (const float*)d_in[11];
  const float* Wv1 = (const float*)d_in[12]; const float* bv1 = (const float*)d_in[13];
  const float* Wo1 = (const float*)d_in[14]; const float* bo1 = (const float*)d_in[15];
  const float* Wq2 = (const float*)d_in[16]; const float* bq2 = (const float*)d_in[17];
  const float* Wk2 = (const float*)d_in[18]; const float* bk2 = (const float*)d_in[19];
  const float* Wv2 = (const float*)d_in[20]; const float* bv2 = (const float*)d_in[21];
  const float* Wo2 = (const float*)d_in[22]; const float* bo2 = (const float*)d_in[23];
  const float* Wup = (const float*)d_in[24]; const float* bup = (const float*)d_in[25];
  const float* Wdn = (const float*)d_in[26]; const float* bdn = (const float*)d_in[27];

  char* ws = (char*)d_ws;
  const size_t MB = 1ull << 20;
  u16*   wpack  = (u16*)(ws);
  u16*   enc_bf = (u16*)(ws + 8 * MB);
  u16*   h_bf   = (u16*)(ws + 16 * MB);
  u16*   Qb     = (u16*)(ws + 24 * MB);
  u16*   Kbf    = (u16*)(ws + 32 * MB);
  u16*   VTb    = (u16*)(ws + 40 * MB);
  u16*   att_o  = (u16*)(ws + 48 * MB);
  float* x2     = (float*)(ws + 56 * MB);
  float* x3     = (float*)(ws + 72 * MB);
  u16*   ffmid  = (u16*)(ws + 24 * MB);

  const dim3 T(256);

  // ---- block 1: self attention ----
  ln_kernel<<<4096, T, 0, stream>>>(x, ln1_g, ln1_b, h_bf);
  cast_kernel<<<4096, T, 0, stream>>>(enc, enc_bf);
  tp_kernel<<<dim3(1, 16, 16), T, 0, stream>>>(Wq1, wpack,               64, 65536L, 65536L, 1024);
  tp_kernel<<<dim3(1, 16, 16), T, 0, stream>>>(Wk1, wpack + 1024 * 1024, 64, 65536L, 65536L, 1024);
  tp_kernel<<<dim3(1, 16, 16), T, 0, stream>>>(Wv1, wpack + 2048 * 1024, 64, 65536L, 65536L, 1024);
  gemm_kernel<4, 0><<<dim3(24, 32), T, 0, stream>>>(h_bf, wpack, bq1, bk1, bv1, nullptr,
      Qb, Kbf, VTb, nullptr, 4096, 3072, 1024);
  attn_kernel<<<dim3(16, 64), T, 0, stream>>>(Qb, Kbf, VTb, att_o, 1);
  tp_kernel<<<dim3(16, 16, 1), T, 0, stream>>>(Wo1, wpack, 1024, 0L, 0L, 1024);
  gemm_kernel<2, 3><<<dim3(8, 64), T, 0, stream>>>(att_o, wpack, bo1, nullptr, nullptr, x,
      nullptr, nullptr, nullptr, x2, 4096, 1024, 1024);

  // ---- block 2: cross attention (K/V from raw enc) ----
  ln_kernel<<<4096, T, 0, stream>>>(x2, ln2_g, ln2_b, h_bf);
  tp_kernel<<<dim3(1, 16, 16), T, 0, stream>>>(Wq2, wpack, 64, 65536L, 65536L, 1024);
  gemm_kernel<2, 2><<<dim3(8, 64), T, 0, stream>>>(h_bf, wpack, bq2, nullptr, nullptr, nullptr,
      Qb, nullptr, nullptr, nullptr, 4096, 1024, 1024);
  tp_kernel<<<dim3(1, 16, 16), T, 0, stream>>>(Wk2, wpack,               64, 65536L, 65536L, 1024);
  tp_kernel<<<dim3(1, 16, 16), T, 0, stream>>>(Wv2, wpack + 1024 * 1024, 64, 65536L, 65536L, 1024);
  gemm_kernel<4, 1><<<dim3(16, 32), T, 0, stream>>>(enc_bf, wpack, bk2, bv2, nullptr, nullptr,
      Kbf, VTb, nullptr, nullptr, 4096, 2048, 1024);
  attn_kernel<<<dim3(16, 64), T, 0, stream>>>(Qb, Kbf, VTb, att_o, 0);
  tp_kernel<<<dim3(16, 16, 1), T, 0, stream>>>(Wo2, wpack, 1024, 0L, 0L, 1024);
  gemm_kernel<2, 3><<<dim3(8, 64), T, 0, stream>>>(att_o, wpack, bo2, nullptr, nullptr, x2,
      nullptr, nullptr, nullptr, x3, 4096, 1024, 1024);

  // ---- block 3: FFN ----
  ln_kernel<<<4096, T, 0, stream>>>(x3, ln3_g, ln3_b, h_bf);
  tp_kernel<<<dim3(64, 16, 1), T, 0, stream>>>(Wup, wpack, 4096, 0L, 0L, 1024);
  gemm_kernel<4, 4><<<dim3(32, 32), T, 0, stream>>>(h_bf, wpack, bup, nullptr, nullptr, nullptr,
      ffmid, nullptr, nullptr, nullptr, 4096, 4096, 1024);
  tp_kernel<<<dim3(16, 64, 1), T, 0, stream>>>(Wdn, wpack, 1024, 0L, 0L, 4096);
  gemm_kernel<2, 3><<<dim3(8, 64), T, 0, stream>>>(ffmid, wpack, bdn, nullptr, nullptr, x3,
      nullptr, nullptr, nullptr, (float*)d_out, 4096, 1024, 4096);
}